// Round 16
// baseline (153.501 us; speedup 1.0000x reference)
//
#include <hip/hip_runtime.h>
#include <math.h>

#define E_TOTAL 100000
#define N_PAIRS 3125   // 6250 tiles / 2 per wave

typedef __attribute__((ext_vector_type(4))) float f32x4;
typedef __attribute__((ext_vector_type(8))) short bf16x8;

__device__ unsigned short g_fc2H[36864];   // bf16 weights: [col*16 + k]

__device__ __forceinline__ unsigned short f2bf(float x) {
  unsigned int u = __float_as_uint(x);
  u += 0x7fffu + ((u >> 16) & 1u);      // round-to-nearest-even
  return (unsigned short)(u >> 16);
}
__device__ __forceinline__ float bf2f(unsigned short h) {
  return __uint_as_float(((unsigned int)h) << 16);
}

// g_fc2H[col*16 + k] = bf16(fc_w2[k][col] * 0.25f)  (R11-probe-verified source)
__global__ void prep_fc2h_kernel(const float* __restrict__ fw2) {
  int tid = blockIdx.x * 256 + threadIdx.x;   // 144*256 = 36864 exactly
  int col = tid >> 4;
  int k   = tid & 15;
  g_fc2H[tid] = f2bf(fw2[k * 2304 + col] * 0.25f);    // tid == col*16+k
}

// ===== R15 (passing, 53.7us) + 2 edge-tiles per wave: each B triple feeds
// 6 MFMAs (2 afrags) -> weight L2 traffic and loop overhead halve, ILP 2x.
// Runtime loop bounds (no full unroll / no spill); NO unroll pragmas on
// MFMA loops (R13: pragma -> miscompile). All acc registers named (rule #20).
__global__ __launch_bounds__(64) void tp_kernel(
    const float* __restrict__ feature,   // (20000, 80)
    const int*   __restrict__ edge,      // (2, 100000)
    const float* __restrict__ elem,      // (100000, 10)
    const float* __restrict__ esh,       // (100000, 4)
    const float* __restrict__ fw1,       // (10, 16)
    float* __restrict__ out,             // (100000, 80)
    float silu_c, int n1, int n2)
{
  __shared__ float fc1P[160];
  __shared__ float elemP[2][160];
  __shared__ __align__(16) float s1P[2][32][20];
  __shared__ __align__(16) float v1P[2][16][3][20];
  __shared__ __align__(16) float dP[2][16][16];
  __shared__ __align__(16) float hP[2][16][16];
  __shared__ float s2P[2][16], v2P[2][3][16];
  __shared__ int dstP[2][16];

  const int l      = threadIdx.x;       // 64 threads = 1 wave
  const int lane16 = l & 15;
  const int quad   = l >> 4;
  const int quad4  = quad * 4;
  const int eg0    = blockIdx.x * 32;   // grid = 3125 exactly; 32 edges/block

  // ---- stage per-pair inputs (all contiguous/coalesced) ----
  for (int i = l; i < 160; i += 64) fc1P[i] = fw1[i] / sqrtf(10.0f);
  for (int i = l; i < 320; i += 64) ((float*)elemP)[i] = elem[eg0 * 10 + i];
  if (l < 32) ((int*)dstP)[l] = edge[E_TOTAL + eg0 + l];
  for (int i = l; i < 128; i += 64) {
    float v = esh[eg0 * 4 + i];
    int t = i >> 6, e = (i >> 2) & 15, c = i & 3;
    if (c == 0) s2P[t][e] = v; else v2P[t][c - 1][e] = v;
  }
  __syncthreads();

  // ---- feature gather: lane = channel, loop edges x 2 tiles ----
  {
    const int c0 = l;
    const int u0 = (c0 - 32) / 3, i0 = (c0 - 32) % 3;   // used only when c0 >= 32
    for (int t = 0; t < 2; ++t) {
      for (int e = 0; e < 16; ++e) {
        int base = dstP[t][e] * 80;
        float v = feature[base + c0];
        if (c0 < 32) s1P[t][c0][e] = v; else v1P[t][u0][i0][e] = v;
      }
    }
    if (l < 16) {
      const int c1 = 64 + l;
      const int u1 = (c1 - 32) / 3, i1 = (c1 - 32) % 3;
      for (int t = 0; t < 2; ++t)
        for (int e = 0; e < 16; ++e)
          v1P[t][u1][i1][e] = feature[dstP[t][e] * 80 + c1];
    }
  }
  __syncthreads();

  // ---- h = SILU_C * silu(elem @ fc1) ; dP[t][u][e] = v1.v2 ----
  for (int t = 0; t < 2; ++t) {
    const int e = lane16;
    for (int q = 0; q < 4; ++q) {
      int k = quad + 4 * q;
      float a = 0.f;
      for (int j = 0; j < 10; ++j)
        a = fmaf(elemP[t][e * 10 + j], fc1P[j * 16 + k], a);
      hP[t][e][k] = silu_c * a / (1.f + __expf(-a));
    }
    for (int q = 0; q < 4; ++q) {
      int u = quad + 4 * q;
      dP[t][u][e] = v1P[t][u][0][e] * v2P[t][0][e] + v1P[t][u][1][e] * v2P[t][1][e]
                  + v1P[t][u][2][e] * v2P[t][2][e];
    }
  }
  __syncthreads();

  // ---- A fragments (verified construction), one per tile ----
  bf16x8 afA, afB;
  {
    const int k0 = (quad & 1) * 8;
    const bool lo_half = (quad >= 2);
    for (int i = 0; i < 8; ++i) {
      float hv = hP[0][lane16][k0 + i];
      unsigned short hi = f2bf(hv);
      afA[i] = (short)(lo_half ? f2bf(hv - bf2f(hi)) : hi);
    }
    for (int i = 0; i < 8; ++i) {
      float hv = hP[1][lane16][k0 + i];
      unsigned short hi = f2bf(hv);
      afB[i] = (short)(lo_half ? f2bf(hv - bf2f(hi)) : hi);
    }
  }

  const f32x4 zero4 = {0.f, 0.f, 0.f, 0.f};
  const unsigned int* FU  = (const unsigned int*)g_fc2H;
  const unsigned int* FUq = FU + lane16 * 8 + (quad & 1) * 4;

  f32x4 as0aA = zero4, as0bA = zero4, at1A = zero4, as3aA = zero4, as3bA = zero4;
  f32x4 at2aA = zero4, at2bA = zero4, at2cA = zero4;
  f32x4 as0aB = zero4, as0bB = zero4, at1B = zero4, as3aB = zero4, as3bB = zero4;
  f32x4 at2aB = zero4, at2bB = zero4, at2cB = zero4;

  // ---- loop 1 (W0/W1): runtime bound n1(=32), NO pragma ----
  for (int s = 0; s < n1; ++s) {
    bf16x8 b0 = *(const bf16x8*)(FUq + s * 256);           // W0 col s*32+lane16
    bf16x8 b1 = *(const bf16x8*)(FUq + s * 256 + 128);     // W0 col +16
    bf16x8 b2 = *(const bf16x8*)(FUq + 8192 + s * 128);    // W1 col 1024+s*16+lane16
    f32x4 e0A = __builtin_amdgcn_mfma_f32_16x16x32_bf16(afA, b0, zero4, 0, 0, 0);
    f32x4 e1A = __builtin_amdgcn_mfma_f32_16x16x32_bf16(afA, b1, zero4, 0, 0, 0);
    f32x4 e2A = __builtin_amdgcn_mfma_f32_16x16x32_bf16(afA, b2, zero4, 0, 0, 0);
    f32x4 e0B = __builtin_amdgcn_mfma_f32_16x16x32_bf16(afB, b0, zero4, 0, 0, 0);
    f32x4 e1B = __builtin_amdgcn_mfma_f32_16x16x32_bf16(afB, b1, zero4, 0, 0, 0);
    f32x4 e2B = __builtin_amdgcn_mfma_f32_16x16x32_bf16(afB, b2, zero4, 0, 0, 0);
    f32x4 s1vA = *(const f32x4*)&s1P[0][s][quad4];
    f32x4 s1vB = *(const f32x4*)&s1P[1][s][quad4];
    as0aA += e0A * s1vA;   // d[r] = W[edge=quad4+r][col]  (R8+R11+R12 verified)
    as0bA += e1A * s1vA;
    at1A  += e2A * s1vA;
    as0aB += e0B * s1vB;
    as0bB += e1B * s1vB;
    at1B  += e2B * s1vB;
  }

  // ---- loop 2 (W2/W3): runtime bound n2(=16), NO pragma ----
  for (int v = 0; v < n2; ++v) {
    bf16x8 b0 = *(const bf16x8*)(FUq + 12288 + v * 128);         // W2
    bf16x8 b1 = *(const bf16x8*)(FUq + 14336 + v * 256);         // W3 lo16
    bf16x8 b2 = *(const bf16x8*)(FUq + 14336 + v * 256 + 128);   // W3 hi16
    f32x4 e0A = __builtin_amdgcn_mfma_f32_16x16x32_bf16(afA, b0, zero4, 0, 0, 0);
    f32x4 e1A = __builtin_amdgcn_mfma_f32_16x16x32_bf16(afA, b1, zero4, 0, 0, 0);
    f32x4 e2A = __builtin_amdgcn_mfma_f32_16x16x32_bf16(afA, b2, zero4, 0, 0, 0);
    f32x4 e0B = __builtin_amdgcn_mfma_f32_16x16x32_bf16(afB, b0, zero4, 0, 0, 0);
    f32x4 e1B = __builtin_amdgcn_mfma_f32_16x16x32_bf16(afB, b1, zero4, 0, 0, 0);
    f32x4 e2B = __builtin_amdgcn_mfma_f32_16x16x32_bf16(afB, b2, zero4, 0, 0, 0);
    f32x4 v0A = *(const f32x4*)&v1P[0][v][0][quad4];
    f32x4 v1A = *(const f32x4*)&v1P[0][v][1][quad4];
    f32x4 v2A = *(const f32x4*)&v1P[0][v][2][quad4];
    f32x4 dvA = *(const f32x4*)&dP[0][v][quad4];
    f32x4 v0B = *(const f32x4*)&v1P[1][v][0][quad4];
    f32x4 v1B = *(const f32x4*)&v1P[1][v][1][quad4];
    f32x4 v2B = *(const f32x4*)&v1P[1][v][2][quad4];
    f32x4 dvB = *(const f32x4*)&dP[1][v][quad4];
    at2aA += e0A * v0A;
    at2bA += e0A * v1A;
    at2cA += e0A * v2A;
    as3aA += e1A * dvA;
    as3bA += e2A * dvA;
    at2aB += e0B * v0B;
    at2bB += e0B * v1B;
    at2cB += e0B * v2B;
    as3aB += e1B * dvB;
    as3bB += e2B * dvB;
  }

  // ---- epilogue, tile 0 then tile 1 (R12-verbatim frame) ----
  const float CC = 0.14433756729740643f;  // 1/sqrt(48) = C0 = C1 = C2; C3 = 0.25
  {
    f32x4 s2v = *(const f32x4*)&s2P[0][quad4];
    f32x4 v20 = *(const f32x4*)&v2P[0][0][quad4];
    f32x4 v21 = *(const f32x4*)&v2P[0][1][quad4];
    f32x4 v22 = *(const f32x4*)&v2P[0][2][quad4];
    for (int r = 0; r < 4; ++r) {
      int e = eg0 + quad4 + r;
      float* op = out + (size_t)e * 80;
      op[lane16]      = CC * s2v[r] * as0aA[r] + 0.25f * as3aA[r];
      op[16 + lane16] = CC * s2v[r] * as0bA[r] + 0.25f * as3bA[r];
      float t1r = at1A[r];
      float* vp = op + 32 + lane16 * 3;
      vp[0] = CC * (v20[r] * t1r + s2v[r] * at2aA[r]);
      vp[1] = CC * (v21[r] * t1r + s2v[r] * at2bA[r]);
      vp[2] = CC * (v22[r] * t1r + s2v[r] * at2cA[r]);
    }
  }
  {
    f32x4 s2v = *(const f32x4*)&s2P[1][quad4];
    f32x4 v20 = *(const f32x4*)&v2P[1][0][quad4];
    f32x4 v21 = *(const f32x4*)&v2P[1][1][quad4];
    f32x4 v22 = *(const f32x4*)&v2P[1][2][quad4];
    for (int r = 0; r < 4; ++r) {
      int e = eg0 + 16 + quad4 + r;
      float* op = out + (size_t)e * 80;
      op[lane16]      = CC * s2v[r] * as0aB[r] + 0.25f * as3aB[r];
      op[16 + lane16] = CC * s2v[r] * as0bB[r] + 0.25f * as3bB[r];
      float t1r = at1B[r];
      float* vp = op + 32 + lane16 * 3;
      vp[0] = CC * (v20[r] * t1r + s2v[r] * at2aB[r]);
      vp[1] = CC * (v21[r] * t1r + s2v[r] * at2bB[r]);
      vp[2] = CC * (v22[r] * t1r + s2v[r] * at2cB[r]);
    }
  }
}

// Host-side SILU_C, memoized (R14 lesson: ~1.2ms of host exp() per call
// tripped the fresh-launch-vs-replay timing check).
static float get_silu_c() {
  static float cached = -1.0f;
  if (cached < 0.0f) {
    const int NPTS = 200001;
    const double dx = 24.0 / 200000.0;
    const double inv_sqrt2pi = 0.3989422804014326779;
    double sum = 0.0;
    double x0 = -12.0;
    double s0 = x0 / (1.0 + exp(-x0));
    double y0 = s0 * s0 * exp(-0.5 * x0 * x0) * inv_sqrt2pi;
    for (int i = 1; i < NPTS; ++i) {
      double x1 = -12.0 + i * dx;
      double s1 = x1 / (1.0 + exp(-x1));
      double y1 = s1 * s1 * exp(-0.5 * x1 * x1) * inv_sqrt2pi;
      sum += 0.5 * (y0 + y1) * dx;
      y0 = y1;
    }
    cached = (float)(1.0 / sqrt(sum));
  }
  return cached;
}

extern "C" void kernel_launch(void* const* d_in, const int* in_sizes, int n_in,
                              void* d_out, int out_size, void* d_ws, size_t ws_size,
                              hipStream_t stream) {
  const float* feature = (const float*)d_in[0];
  const int*   edge    = (const int*)d_in[1];
  const float* elem    = (const float*)d_in[2];
  const float* esh     = (const float*)d_in[3];
  const float* fw1     = (const float*)d_in[4];
  const float* fw2     = (const float*)d_in[5];
  float* out = (float*)d_out;
  (void)d_ws; (void)ws_size;

  float silu_c = get_silu_c();

  hipLaunchKernelGGL(prep_fc2h_kernel, dim3(144), dim3(256), 0, stream, fw2);
  hipLaunchKernelGGL(tp_kernel, dim3(N_PAIRS), dim3(64), 0, stream,
                     feature, edge, elem, esh, fw1, out, silu_c, 32, 16);
}

// Round 17
// 123.721 us; speedup vs baseline: 1.2407x; 1.2407x over previous
//
#include <hip/hip_runtime.h>
#include <math.h>

#define E_TOTAL 100000
#define N_TILES 6250   // E_TOTAL / 16

typedef __attribute__((ext_vector_type(4))) float f32x4;
typedef __attribute__((ext_vector_type(8))) short bf16x8;

__device__ unsigned short g_fc2H[36864];   // bf16 weights: [col*16 + k]

__device__ __forceinline__ unsigned short f2bf(float x) {
  unsigned int u = __float_as_uint(x);
  u += 0x7fffu + ((u >> 16) & 1u);      // round-to-nearest-even
  return (unsigned short)(u >> 16);
}
__device__ __forceinline__ float bf2f(unsigned short h) {
  return __uint_as_float(((unsigned int)h) << 16);
}

// g_fc2H[col*16 + k] = bf16(fc_w2[k][col] * 0.25f)  (R11-probe-verified source)
__global__ void prep_fc2h_kernel(const float* __restrict__ fw2) {
  int tid = blockIdx.x * 256 + threadIdx.x;   // 144*256 = 36864 exactly
  int col = tid >> 4;
  int k   = tid & 15;
  g_fc2H[tid] = f2bf(fw2[k * 2304 + col] * 0.25f);    // tid == col*16+k
}

// ===== R15 (passing, 53.7us ctr) + manual depth-1 register pipeline on the
// B-fragment loads: prefetch slab s+1 into named regs during MFMA(s), so the
// ~250cy L2 latency overlaps compute instead of serializing per iteration.
// R16 lesson: occupancy (15 blocks/CU at 10.2KB LDS) is the controlling
// variable - this change keeps LDS byte-identical. Runtime loop bounds
// (no full unroll / no spill); NO unroll pragmas on MFMA loops (R13).
__global__ __launch_bounds__(64) void tp_kernel(
    const float* __restrict__ feature,   // (20000, 80)
    const int*   __restrict__ edge,      // (2, 100000)
    const float* __restrict__ elem,      // (100000, 10)
    const float* __restrict__ esh,       // (100000, 4)
    const float* __restrict__ fw1,       // (10, 16)
    float* __restrict__ out,             // (100000, 80)
    float silu_c, int n1, int n2)
{
  __shared__ float fc1P[160], elemP[160];
  __shared__ __align__(16) float s1P[32][20];
  __shared__ __align__(16) float v1P[16][3][20];
  __shared__ __align__(16) float dP[16][16];
  __shared__ __align__(16) float hP[16][16];
  __shared__ float s2P[16], v2P[3][16];
  __shared__ int dstP[16];

  const int l      = threadIdx.x;       // 64 threads = 1 wave
  const int lane16 = l & 15;
  const int quad   = l >> 4;
  const int quad4  = quad * 4;
  const int eg0    = blockIdx.x * 16;   // grid = 6250 exactly

  // ---- stage per-tile inputs (R15-verbatim) ----
  for (int i = l; i < 160; i += 64) {
    fc1P[i]  = fw1[i] / sqrtf(10.0f);
    elemP[i] = elem[eg0 * 10 + i];
  }
  if (l < 16) dstP[l] = edge[E_TOTAL + eg0 + l];
  {
    float v = esh[eg0 * 4 + l];
    int e = l >> 2, c = l & 3;
    if (c == 0) s2P[e] = v; else v2P[c - 1][e] = v;
  }
  __syncthreads();

  // ---- feature gather (R15-verbatim) ----
  {
    const int c0 = l;
    const int u0 = (c0 - 32) / 3, i0 = (c0 - 32) % 3;
    for (int e = 0; e < 16; ++e) {
      int base = dstP[e] * 80;
      float v = feature[base + c0];
      if (c0 < 32) s1P[c0][e] = v; else v1P[u0][i0][e] = v;
    }
    if (l < 16) {
      const int c1 = 64 + l;
      const int u1 = (c1 - 32) / 3, i1 = (c1 - 32) % 3;
      for (int e = 0; e < 16; ++e)
        v1P[u1][i1][e] = feature[dstP[e] * 80 + c1];
    }
  }
  __syncthreads();

  // ---- h = SILU_C * silu(elem @ fc1) ; dP[u][e] = v1[u,:].v2 (R15-verbatim) ----
  {
    const int e = lane16;
    for (int q = 0; q < 4; ++q) {
      int k = quad + 4 * q;
      float a = 0.f;
      for (int j = 0; j < 10; ++j)
        a = fmaf(elemP[e * 10 + j], fc1P[j * 16 + k], a);
      hP[e][k] = silu_c * a / (1.f + __expf(-a));
    }
    for (int q = 0; q < 4; ++q) {
      int u = quad + 4 * q;
      dP[u][e] = v1P[u][0][e] * v2P[0][e] + v1P[u][1][e] * v2P[1][e]
               + v1P[u][2][e] * v2P[2][e];
    }
  }
  __syncthreads();

  // ---- A fragment (verified): [hi(h)0..15 | lo(h)0..15], chunk by quad ----
  bf16x8 afrag;
  {
    const int k0 = (quad & 1) * 8;
    const bool lo_half = (quad >= 2);
    for (int i = 0; i < 8; ++i) {
      float hv = hP[lane16][k0 + i];
      unsigned short hi = f2bf(hv);
      afrag[i] = (short)(lo_half ? f2bf(hv - bf2f(hi)) : hi);
    }
  }

  const f32x4 zero4 = {0.f, 0.f, 0.f, 0.f};
  const unsigned int* FU  = (const unsigned int*)g_fc2H;
  const unsigned int* FUq = FU + lane16 * 8 + (quad & 1) * 4;

  f32x4 as0a = zero4, as0b = zero4, at1 = zero4, as3a = zero4, as3b = zero4;
  f32x4 at2a = zero4, at2b = zero4, at2c = zero4;

  // ---- loop 1 (W0/W1): depth-1 register pipeline, runtime bound, NO pragma ----
  bf16x8 cb0 = *(const bf16x8*)(FUq);          // s=0 slab
  bf16x8 cb1 = *(const bf16x8*)(FUq + 128);
  bf16x8 cb2 = *(const bf16x8*)(FUq + 8192);
  for (int s = 0; s < n1; ++s) {
    const int sn = (s + 1 < n1) ? s + 1 : 0;   // clamped: always in-bounds, no branch
    bf16x8 nb0 = *(const bf16x8*)(FUq + sn * 256);
    bf16x8 nb1 = *(const bf16x8*)(FUq + sn * 256 + 128);
    bf16x8 nb2 = *(const bf16x8*)(FUq + 8192 + sn * 128);
    f32x4 e0 = __builtin_amdgcn_mfma_f32_16x16x32_bf16(afrag, cb0, zero4, 0, 0, 0);
    f32x4 e1 = __builtin_amdgcn_mfma_f32_16x16x32_bf16(afrag, cb1, zero4, 0, 0, 0);
    f32x4 e2 = __builtin_amdgcn_mfma_f32_16x16x32_bf16(afrag, cb2, zero4, 0, 0, 0);
    f32x4 s1v = *(const f32x4*)&s1P[s][quad4];
    as0a += e0 * s1v;     // d[r] = W[edge=quad4+r][col]  (R8+R11+R12 verified)
    as0b += e1 * s1v;
    at1  += e2 * s1v;
    cb0 = nb0; cb1 = nb1; cb2 = nb2;
  }

  // ---- loop 2 (W2/W3): depth-1 register pipeline, runtime bound, NO pragma ----
  cb0 = *(const bf16x8*)(FUq + 12288);         // v=0 slab
  cb1 = *(const bf16x8*)(FUq + 14336);
  cb2 = *(const bf16x8*)(FUq + 14336 + 128);
  for (int v = 0; v < n2; ++v) {
    const int vn = (v + 1 < n2) ? v + 1 : 0;
    bf16x8 nb0 = *(const bf16x8*)(FUq + 12288 + vn * 128);
    bf16x8 nb1 = *(const bf16x8*)(FUq + 14336 + vn * 256);
    bf16x8 nb2 = *(const bf16x8*)(FUq + 14336 + vn * 256 + 128);
    f32x4 e0 = __builtin_amdgcn_mfma_f32_16x16x32_bf16(afrag, cb0, zero4, 0, 0, 0);
    f32x4 e1 = __builtin_amdgcn_mfma_f32_16x16x32_bf16(afrag, cb1, zero4, 0, 0, 0);
    f32x4 e2 = __builtin_amdgcn_mfma_f32_16x16x32_bf16(afrag, cb2, zero4, 0, 0, 0);
    f32x4 v1v0 = *(const f32x4*)&v1P[v][0][quad4];
    f32x4 v1v1 = *(const f32x4*)&v1P[v][1][quad4];
    f32x4 v1v2 = *(const f32x4*)&v1P[v][2][quad4];
    f32x4 dv   = *(const f32x4*)&dP[v][quad4];
    at2a += e0 * v1v0;
    at2b += e0 * v1v1;
    at2c += e0 * v1v2;
    as3a += e1 * dv;
    as3b += e2 * dv;
    cb0 = nb0; cb1 = nb1; cb2 = nb2;
  }

  // ---- epilogue (R15-verbatim) ----
  f32x4 s2v = *(const f32x4*)&s2P[quad4];
  f32x4 v20 = *(const f32x4*)&v2P[0][quad4];
  f32x4 v21 = *(const f32x4*)&v2P[1][quad4];
  f32x4 v22 = *(const f32x4*)&v2P[2][quad4];
  const float CC = 0.14433756729740643f;  // 1/sqrt(48) = C0 = C1 = C2; C3 = 0.25
  for (int r = 0; r < 4; ++r) {
    int e = eg0 + quad4 + r;
    float* op = out + (size_t)e * 80;
    op[lane16]      = CC * s2v[r] * as0a[r] + 0.25f * as3a[r];
    op[16 + lane16] = CC * s2v[r] * as0b[r] + 0.25f * as3b[r];
    float t1r = at1[r];
    float* vp = op + 32 + lane16 * 3;
    vp[0] = CC * (v20[r] * t1r + s2v[r] * at2a[r]);
    vp[1] = CC * (v21[r] * t1r + s2v[r] * at2b[r]);
    vp[2] = CC * (v22[r] * t1r + s2v[r] * at2c[r]);
  }
}

// Host-side SILU_C, memoized (R14 lesson: ~1.2ms host exp() per call tripped
// the fresh-launch-vs-replay timing check).
static float get_silu_c() {
  static float cached = -1.0f;
  if (cached < 0.0f) {
    const int NPTS = 200001;
    const double dx = 24.0 / 200000.0;
    const double inv_sqrt2pi = 0.3989422804014326779;
    double sum = 0.0;
    double x0 = -12.0;
    double s0 = x0 / (1.0 + exp(-x0));
    double y0 = s0 * s0 * exp(-0.5 * x0 * x0) * inv_sqrt2pi;
    for (int i = 1; i < NPTS; ++i) {
      double x1 = -12.0 + i * dx;
      double s1 = x1 / (1.0 + exp(-x1));
      double y1 = s1 * s1 * exp(-0.5 * x1 * x1) * inv_sqrt2pi;
      sum += 0.5 * (y0 + y1) * dx;
      y0 = y1;
    }
    cached = (float)(1.0 / sqrt(sum));
  }
  return cached;
}

extern "C" void kernel_launch(void* const* d_in, const int* in_sizes, int n_in,
                              void* d_out, int out_size, void* d_ws, size_t ws_size,
                              hipStream_t stream) {
  const float* feature = (const float*)d_in[0];
  const int*   edge    = (const int*)d_in[1];
  const float* elem    = (const float*)d_in[2];
  const float* esh     = (const float*)d_in[3];
  const float* fw1     = (const float*)d_in[4];
  const float* fw2     = (const float*)d_in[5];
  float* out = (float*)d_out;
  (void)d_ws; (void)ws_size;

  float silu_c = get_silu_c();

  hipLaunchKernelGGL(prep_fc2h_kernel, dim3(144), dim3(256), 0, stream, fw2);
  hipLaunchKernelGGL(tp_kernel, dim3(N_TILES), dim3(64), 0, stream,
                     feature, edge, elem, esh, fw1, out, silu_c, 32, 16);
}